// Round 1
// baseline (492.937 us; speedup 1.0000x reference)
//
#include <hip/hip_runtime.h>

// Problem constants (fixed by the reference).
#define NNODES 100000
#define NEDGES 800000
#define DIN    128
#define HID    64
#define EMB    32
#define NIDX   50000
#define BN_EPS 1e-5f

// ---------------------------------------------------------------------------
// CSR build: histogram -> block scan -> scatter. Rebuilt every call (ws is
// re-poisoned). Cost is ~2.5MB of traffic + 1.6M int atomics, a few us.
// ---------------------------------------------------------------------------

__global__ void hist_k(const int* __restrict__ rows, int* __restrict__ cnt, int E) {
    int e = blockIdx.x * 256 + threadIdx.x;
    if (e < E) atomicAdd(&cnt[rows[e]], 1);
}

__global__ void scan1_k(const int* __restrict__ cnt, int* __restrict__ part, int n) {
    __shared__ int s[256];
    int i = blockIdx.x * 256 + threadIdx.x;
    s[threadIdx.x] = (i < n) ? cnt[i] : 0;
    __syncthreads();
    for (int off = 128; off > 0; off >>= 1) {
        if (threadIdx.x < off) s[threadIdx.x] += s[threadIdx.x + off];
        __syncthreads();
    }
    if (threadIdx.x == 0) part[blockIdx.x] = s[0];
}

__global__ void scan2_k(int* part, int nb) {
    __shared__ int s[512];
    int t = threadIdx.x;
    int v = (t < nb) ? part[t] : 0;
    s[t] = v;
    __syncthreads();
    for (int off = 1; off < 512; off <<= 1) {
        int a = (t >= off) ? s[t - off] : 0;
        __syncthreads();
        s[t] += a;
        __syncthreads();
    }
    if (t < nb) part[t] = s[t] - v;   // exclusive prefix of block sums
}

__global__ void scan3_k(const int* __restrict__ cnt, const int* __restrict__ part,
                        int* __restrict__ rowptr, int* __restrict__ cursor, int n, int E) {
    __shared__ int s[256];
    int t = threadIdx.x;
    int i = blockIdx.x * 256 + t;
    int v = (i < n) ? cnt[i] : 0;
    s[t] = v;
    __syncthreads();
    for (int off = 1; off < 256; off <<= 1) {
        int a = (t >= off) ? s[t - off] : 0;
        __syncthreads();
        s[t] += a;
        __syncthreads();
    }
    if (i < n) {
        int ex = part[blockIdx.x] + s[t] - v;   // exclusive
        rowptr[i] = ex;
        cursor[i] = ex;
    }
    if (i == 0) rowptr[n] = E;
}

__global__ void scatter_k(const int* __restrict__ rows, const int* __restrict__ cols,
                          const float* __restrict__ vals, int* __restrict__ cursor,
                          int* __restrict__ col_s, float* __restrict__ val_s, int E) {
    int e = blockIdx.x * 256 + threadIdx.x;
    if (e < E) {
        int r = rows[e];
        int p = atomicAdd(&cursor[r], 1);
        col_s[p] = cols[e];
        val_s[p] = vals[e];
    }
}

// ---------------------------------------------------------------------------
// Fused dual GEMM: Hn = act(X) @ Wn + biases, Hg = act(X) @ Wg + bias.
// act = optional per-column BN affine + ReLU applied while staging X in LDS
// (folds the previous layer's batchnorm+relu for free).
// 32-row tile per 256-thread block; each thread: RPT rows x 4 cols in regs.
// ---------------------------------------------------------------------------

template <int K, int HOUT, bool AFF>
__global__ __launch_bounds__(256) void gemm2_k(
    const float* __restrict__ X,
    const float* __restrict__ Wn, const float* __restrict__ Wg,   // (K, HOUT) row-major
    const float* __restrict__ bnA, const float* __restrict__ bnB, // optional biases, n-side
    const float* __restrict__ bgA,                                // optional bias, g-side
    const float* __restrict__ scale, const float* __restrict__ shift, // AFF: per-k affine
    float* __restrict__ Hn, float* __restrict__ Hg, int n)
{
    constexpr int BR   = 32;
    constexpr int LDK  = K + 4;            // pad keeps 16B alignment, breaks bank stride
    constexpr int COLG = 2 * HOUT / 4;     // 4-col groups across [Hn | Hg]
    constexpr int RPT  = BR * COLG / 256;  // rows per thread
    __shared__ float Xs[BR * LDK];

    const int row0 = blockIdx.x * BR;
    const int t = threadIdx.x;

    // Stage X tile (coalesced float4), applying BN affine + ReLU on the fly.
    constexpr int NV4 = BR * K / 4;
    for (int li = t; li < NV4; li += 256) {
        int r  = li / (K / 4);
        int k4 = (li % (K / 4)) * 4;
        int rr = row0 + r;
        float4 v = make_float4(0.f, 0.f, 0.f, 0.f);
        if (rr < n) v = *(const float4*)&X[(size_t)rr * K + k4];
        if (AFF) {
            float4 sc = *(const float4*)&scale[k4];
            float4 sh = *(const float4*)&shift[k4];
            v.x = fmaxf(v.x * sc.x + sh.x, 0.f);
            v.y = fmaxf(v.y * sc.y + sh.y, 0.f);
            v.z = fmaxf(v.z * sc.z + sh.z, 0.f);
            v.w = fmaxf(v.w * sc.w + sh.w, 0.f);
        }
        *(float4*)&Xs[r * LDK + k4] = v;
    }
    __syncthreads();

    const int cidx = t % COLG;
    const int ridx = t / COLG;
    const int col4 = cidx * 4;
    const bool nside = (col4 < HOUT);
    const float* W = nside ? Wn : Wg;
    const int wcol = nside ? col4 : (col4 - HOUT);

    float acc[RPT][4];
#pragma unroll
    for (int i = 0; i < RPT; i++)
        acc[i][0] = acc[i][1] = acc[i][2] = acc[i][3] = 0.f;

#pragma unroll 4
    for (int k = 0; k < K; k++) {
        float4 w = *(const float4*)&W[k * HOUT + wcol];   // L1-hot
#pragma unroll
        for (int i = 0; i < RPT; i++) {
            float xv = Xs[(ridx * RPT + i) * LDK + k];    // LDS broadcast
            acc[i][0] += xv * w.x;
            acc[i][1] += xv * w.y;
            acc[i][2] += xv * w.z;
            acc[i][3] += xv * w.w;
        }
    }

    float4 b4 = make_float4(0.f, 0.f, 0.f, 0.f);
    if (nside) {
        if (bnA) { float4 u = *(const float4*)&bnA[wcol]; b4.x += u.x; b4.y += u.y; b4.z += u.z; b4.w += u.w; }
        if (bnB) { float4 u = *(const float4*)&bnB[wcol]; b4.x += u.x; b4.y += u.y; b4.z += u.z; b4.w += u.w; }
    } else if (bgA) {
        float4 u = *(const float4*)&bgA[wcol]; b4.x += u.x; b4.y += u.y; b4.z += u.z; b4.w += u.w;
    }

    float* dst = nside ? Hn : Hg;
#pragma unroll
    for (int i = 0; i < RPT; i++) {
        int rr = row0 + ridx * RPT + i;
        if (rr < n) {
            float4 o;
            o.x = acc[i][0] + b4.x;
            o.y = acc[i][1] + b4.y;
            o.z = acc[i][2] + b4.z;
            o.w = acc[i][3] + b4.w;
            *(float4*)&dst[(size_t)rr * HOUT + wcol] = o;
        }
    }
}

// ---------------------------------------------------------------------------
// SpMM (CSR gather): S[row] += sum_e val[e]*Hg[col[e]], one HH-lane group per
// row, grid-stride. Optionally accumulates BN batch statistics (sum, sumsq)
// with block-level reduction + striped atomics (8 stripes kills same-address
// serialization).
// ---------------------------------------------------------------------------

template <int HH, bool STATS>
__global__ __launch_bounds__(256) void spmm_k(
    const int* __restrict__ rowptr, const int* __restrict__ col_s,
    const float* __restrict__ val_s, const float* __restrict__ Hg,
    float* __restrict__ S, float* __restrict__ stats, int n)
{
    constexpr int GP = 256 / HH;           // groups per block
    const int lane = threadIdx.x % HH;
    const int g = threadIdx.x / HH;
    const int gid = blockIdx.x * GP + g;
    const int ngroups = gridDim.x * GP;

    float sum = 0.f, sq = 0.f;
    for (int row = gid; row < n; row += ngroups) {
        int e0 = rowptr[row], e1 = rowptr[row + 1];
        float acc0 = S[(size_t)row * HH + lane];   // h_node (+bias) already here
        float acc1 = 0.f;
        int e = e0;
        for (; e + 1 < e1; e += 2) {               // 2-way unroll: break FMA chain
            int   c0 = col_s[e],   c1 = col_s[e + 1];
            float v0 = val_s[e],   v1 = val_s[e + 1];
            acc0 += v0 * Hg[(size_t)c0 * HH + lane];
            acc1 += v1 * Hg[(size_t)c1 * HH + lane];
        }
        if (e < e1) acc0 += val_s[e] * Hg[(size_t)col_s[e] * HH + lane];
        float acc = acc0 + acc1;
        S[(size_t)row * HH + lane] = acc;
        if (STATS) { sum += acc; sq += acc * acc; }
    }

    if constexpr (STATS) {
        __shared__ float rs[GP][HH];
        __shared__ float rq[GP][HH];
        rs[g][lane] = sum;
        rq[g][lane] = sq;
        __syncthreads();
        if (threadIdx.x < HH) {
            float a = 0.f, b = 0.f;
            for (int w = 0; w < GP; w++) { a += rs[w][threadIdx.x]; b += rq[w][threadIdx.x]; }
            int stripe = blockIdx.x & 7;
            atomicAdd(&stats[stripe * 128 + threadIdx.x], a);
            atomicAdd(&stats[stripe * 128 + HH + threadIdx.x], b);
        }
    }
}

// stats_in: 8 stripes x [sum[64] | sumsq[64]]. Writes BN scale/shift.
__global__ void finalize_k(const float* __restrict__ stats_in,
                           const float* __restrict__ gamma, const float* __restrict__ beta,
                           float* __restrict__ scale, float* __restrict__ shift, float n) {
    int t = threadIdx.x;   // 64
    float sum = 0.f, sq = 0.f;
    for (int s = 0; s < 8; s++) { sum += stats_in[s * 128 + t]; sq += stats_in[s * 128 + 64 + t]; }
    float m = sum / n;
    float var = sq / n - m * m;
    float sc = gamma[t] * rsqrtf(var + BN_EPS);
    scale[t] = sc;
    shift[t] = beta[t] - m * sc;
}

__global__ void gather_k(const float* __restrict__ S, const int* __restrict__ idx,
                         float* __restrict__ out, int total) {
    int j = blockIdx.x * 256 + threadIdx.x;
    if (j < total) {
        int r = j / EMB, c = j % EMB;
        out[j] = S[(size_t)idx[r] * EMB + c];
    }
}

// ---------------------------------------------------------------------------

extern "C" void kernel_launch(void* const* d_in, const int* in_sizes, int n_in,
                              void* d_out, int out_size, void* d_ws, size_t ws_size,
                              hipStream_t stream) {
    const float* features = (const float*)d_in[0];
    const int*   rows     = (const int*)d_in[1];
    const int*   cols     = (const int*)d_in[2];
    const float* vals     = (const float*)d_in[3];
    const int*   idx      = (const int*)d_in[4];
    const float* Wn0 = (const float*)d_in[5];
    const float* bn0 = (const float*)d_in[6];
    const float* Wg0 = (const float*)d_in[7];
    const float* bg0 = (const float*)d_in[8];
    const float* ab0 = (const float*)d_in[9];
    const float* g0  = (const float*)d_in[10];
    const float* b0  = (const float*)d_in[11];
    const float* Wn1 = (const float*)d_in[12];
    const float* Wg1 = (const float*)d_in[13];
    const float* ab1 = (const float*)d_in[14];
    const float* g1  = (const float*)d_in[15];
    const float* b1  = (const float*)d_in[16];
    const float* WnL = (const float*)d_in[17];
    const float* WgL = (const float*)d_in[18];
    const float* abL = (const float*)d_in[19];
    float* out = (float*)d_out;

    // Workspace layout (~85 MB): 3 big activation buffers (reused), CSR, stats.
    float* big0 = (float*)d_ws;                         // Hn0/s0, then HnL/sL
    float* big1 = big0 + (size_t)NNODES * HID;          // Hg0/Hg1, then HgL
    float* big2 = big1 + (size_t)NNODES * HID;          // Hn1/s1
    int*   cnt     = (int*)(big2 + (size_t)NNODES * HID);
    int*   part    = cnt + NNODES;
    int*   rowptr  = part + 1024;
    int*   cursor  = rowptr + NNODES + 1;
    int*   col_s   = cursor + NNODES;
    float* val_s   = (float*)(col_s + NEDGES);
    float* stats   = val_s + NEDGES;
    // stats: [0,1024) sums0 (8 stripes x 128), [1024,2048) sums1,
    //        [2048..) scale0, shift0, scale1, shift1 (64 each)
    float* sums0  = stats;
    float* sums1  = stats + 1024;
    float* scale0 = stats + 2048;
    float* shift0 = stats + 2112;
    float* scale1 = stats + 2176;
    float* shift1 = stats + 2240;

    hipMemsetAsync(cnt, 0, NNODES * sizeof(int), stream);
    hipMemsetAsync(stats, 0, 2048 * sizeof(float), stream);

    const int EB = (NEDGES + 255) / 256;   // 3125
    const int NB = (NNODES + 255) / 256;   // 391
    hist_k<<<EB, 256, 0, stream>>>(rows, cnt, NEDGES);
    scan1_k<<<NB, 256, 0, stream>>>(cnt, part, NNODES);
    scan2_k<<<1, 512, 0, stream>>>(part, NB);
    scan3_k<<<NB, 256, 0, stream>>>(cnt, part, rowptr, cursor, NNODES, NEDGES);
    scatter_k<<<EB, 256, 0, stream>>>(rows, cols, vals, cursor, col_s, val_s, NEDGES);

    const int GB = NNODES / 32;            // 3125 (exact)

    // Layer 0: Hn = X@Wn0 + bn0 + ab0, Hg = X@Wg0 + bg0; s0 = Hn + A@Hg
    gemm2_k<DIN, HID, false><<<GB, 256, 0, stream>>>(
        features, Wn0, Wg0, bn0, ab0, bg0, nullptr, nullptr, big0, big1, NNODES);
    spmm_k<HID, true><<<2048, 256, 0, stream>>>(rowptr, col_s, val_s, big1, big0, sums0, NNODES);
    finalize_k<<<1, 64, 0, stream>>>(sums0, g0, b0, scale0, shift0, (float)NNODES);

    // Layer 1: x1 = relu(BN(s0)) folded into staging; s1 = Hn1 + A@Hg1 + ab1
    gemm2_k<HID, HID, true><<<GB, 256, 0, stream>>>(
        big0, Wn1, Wg1, ab1, nullptr, nullptr, scale0, shift0, big2, big1, NNODES);
    spmm_k<HID, true><<<2048, 256, 0, stream>>>(rowptr, col_s, val_s, big1, big2, sums1, NNODES);
    finalize_k<<<1, 64, 0, stream>>>(sums1, g1, b1, scale1, shift1, (float)NNODES);

    // Last: xL = relu(BN(s1)); sL = xL@WnL + A@(xL@WgL) + abL; out = sL[idx]
    gemm2_k<HID, EMB, true><<<GB, 256, 0, stream>>>(
        big2, WnL, WgL, abL, nullptr, nullptr, scale1, shift1, big0, big1, NNODES);
    spmm_k<EMB, false><<<2048, 256, 0, stream>>>(rowptr, col_s, val_s, big1, big0, nullptr, NNODES);
    gather_k<<<(NIDX * EMB + 255) / 256, 256, 0, stream>>>(big0, idx, out, NIDX * EMB);
}

// Round 2
// 461.803 us; speedup vs baseline: 1.0674x; 1.0674x over previous
//
#include <hip/hip_runtime.h>

// Problem constants (fixed by the reference).
#define NNODES 100000
#define NEDGES 800000
#define DIN    128
#define HID    64
#define EMB    32
#define NIDX   50000
#define BN_EPS 1e-5f

// ---------------------------------------------------------------------------
// CSR build: histogram -> block scan -> scatter. Rebuilt every call (ws is
// re-poisoned). Edges packed as int2{col, val_bits} to halve scatter
// transactions and SpMM scalar loads.
// ---------------------------------------------------------------------------

__global__ void hist_k(const int* __restrict__ rows, int* __restrict__ cnt, int E) {
    int e = blockIdx.x * 256 + threadIdx.x;
    if (e < E) atomicAdd(&cnt[rows[e]], 1);
}

__global__ void scan1_k(const int* __restrict__ cnt, int* __restrict__ part, int n) {
    __shared__ int s[256];
    int i = blockIdx.x * 256 + threadIdx.x;
    s[threadIdx.x] = (i < n) ? cnt[i] : 0;
    __syncthreads();
    for (int off = 128; off > 0; off >>= 1) {
        if (threadIdx.x < off) s[threadIdx.x] += s[threadIdx.x + off];
        __syncthreads();
    }
    if (threadIdx.x == 0) part[blockIdx.x] = s[0];
}

__global__ void scan2_k(int* part, int nb) {
    __shared__ int s[512];
    int t = threadIdx.x;
    int v = (t < nb) ? part[t] : 0;
    s[t] = v;
    __syncthreads();
    for (int off = 1; off < 512; off <<= 1) {
        int a = (t >= off) ? s[t - off] : 0;
        __syncthreads();
        s[t] += a;
        __syncthreads();
    }
    if (t < nb) part[t] = s[t] - v;   // exclusive prefix of block sums
}

__global__ void scan3_k(const int* __restrict__ cnt, const int* __restrict__ part,
                        int* __restrict__ rowptr, int* __restrict__ cursor, int n, int E) {
    __shared__ int s[256];
    int t = threadIdx.x;
    int i = blockIdx.x * 256 + t;
    int v = (i < n) ? cnt[i] : 0;
    s[t] = v;
    __syncthreads();
    for (int off = 1; off < 256; off <<= 1) {
        int a = (t >= off) ? s[t - off] : 0;
        __syncthreads();
        s[t] += a;
        __syncthreads();
    }
    if (i < n) {
        int ex = part[blockIdx.x] + s[t] - v;   // exclusive
        rowptr[i] = ex;
        cursor[i] = ex;
    }
    if (i == 0) rowptr[n] = E;
}

__global__ void scatter_k(const int* __restrict__ rows, const int* __restrict__ cols,
                          const float* __restrict__ vals, int* __restrict__ cursor,
                          int2* __restrict__ cs, int E) {
    int e = blockIdx.x * 256 + threadIdx.x;
    if (e < E) {
        int r = rows[e];
        int p = atomicAdd(&cursor[r], 1);
        cs[p] = make_int2(cols[e], __float_as_int(vals[e]));
    }
}

// ---------------------------------------------------------------------------
// Fused dual GEMM: Hn = act(X) @ Wn (+biases), Hg = act(X) @ Wg (+bias).
// act = optional per-column BN affine + ReLU applied while staging X in LDS.
// BR=128 rows/block, 256 threads; thread owns RPT rows x 4 cols.
// RPT=16 (HOUT=64) keeps W-load L1 demand at 32 B/cyc/CU (< 64 B/cyc TA peak);
// the old RPT=4 demanded 128 B/cyc -> VALUBusy capped ~35%.
// ---------------------------------------------------------------------------

template <int K, int HOUT, bool AFF>
__global__ __launch_bounds__(256) void gemm2_k(
    const float* __restrict__ X,
    const float* __restrict__ Wn, const float* __restrict__ Wg,   // (K, HOUT) row-major
    const float* __restrict__ bnA, const float* __restrict__ bnB, // optional biases, n-side
    const float* __restrict__ bgA,                                // optional bias, g-side
    const float* __restrict__ scale, const float* __restrict__ shift, // AFF: per-k affine
    float* __restrict__ Hn, float* __restrict__ Hg, int n)
{
    constexpr int BR   = 128;
    constexpr int LDK  = K + 4;            // 16B-aligned pad; row stride shifts banks by 4
    constexpr int COLG = 2 * HOUT / 4;     // 4-col groups across [Hn | Hg]
    constexpr int RPG  = 256 / COLG;       // ridx groups
    constexpr int RPT  = BR / RPG;         // rows per thread (16 for H=64, 8 for H=32)
    __shared__ float Xs[BR * LDK];

    const int row0 = blockIdx.x * BR;
    const int t = threadIdx.x;

    // Stage X tile (coalesced float4), applying BN affine + ReLU on the fly.
    constexpr int NV4 = BR * K / 4;
    for (int li = t; li < NV4; li += 256) {
        int r  = li / (K / 4);
        int k4 = (li % (K / 4)) * 4;
        int rr = row0 + r;
        float4 v = make_float4(0.f, 0.f, 0.f, 0.f);
        if (rr < n) v = *(const float4*)&X[(size_t)rr * K + k4];
        if (AFF) {
            float4 sc = *(const float4*)&scale[k4];
            float4 sh = *(const float4*)&shift[k4];
            v.x = fmaxf(v.x * sc.x + sh.x, 0.f);
            v.y = fmaxf(v.y * sc.y + sh.y, 0.f);
            v.z = fmaxf(v.z * sc.z + sh.z, 0.f);
            v.w = fmaxf(v.w * sc.w + sh.w, 0.f);
        }
        *(float4*)&Xs[r * LDK + k4] = v;
    }
    __syncthreads();

    const int cidx = t % COLG;
    const int ridx = t / COLG;
    const int col4 = cidx * 4;
    const bool nside = (col4 < HOUT);
    const float* W = nside ? Wn : Wg;
    const int wcol = nside ? col4 : (col4 - HOUT);
    const float* xrow = &Xs[(ridx * RPT) * LDK];

    float acc[RPT][4];
#pragma unroll
    for (int i = 0; i < RPT; i++)
        acc[i][0] = acc[i][1] = acc[i][2] = acc[i][3] = 0.f;

#pragma unroll 2
    for (int k = 0; k < K; k++) {
        float4 w = *(const float4*)&W[k * HOUT + wcol];   // L1/L2-hot, 1 per 4*RPT FMAs
#pragma unroll
        for (int i = 0; i < RPT; i++) {
            float xv = xrow[i * LDK + k];                 // LDS broadcast (2 addrs/wave)
            acc[i][0] += xv * w.x;
            acc[i][1] += xv * w.y;
            acc[i][2] += xv * w.z;
            acc[i][3] += xv * w.w;
        }
    }

    float4 b4 = make_float4(0.f, 0.f, 0.f, 0.f);
    if (nside) {
        if (bnA) { float4 u = *(const float4*)&bnA[wcol]; b4.x += u.x; b4.y += u.y; b4.z += u.z; b4.w += u.w; }
        if (bnB) { float4 u = *(const float4*)&bnB[wcol]; b4.x += u.x; b4.y += u.y; b4.z += u.z; b4.w += u.w; }
    } else if (bgA) {
        float4 u = *(const float4*)&bgA[wcol]; b4.x += u.x; b4.y += u.y; b4.z += u.z; b4.w += u.w;
    }

    float* dst = nside ? Hn : Hg;
#pragma unroll
    for (int i = 0; i < RPT; i++) {
        int rr = row0 + ridx * RPT + i;
        if (rr < n) {
            float4 o;
            o.x = acc[i][0] + b4.x;
            o.y = acc[i][1] + b4.y;
            o.z = acc[i][2] + b4.z;
            o.w = acc[i][3] + b4.w;
            *(float4*)&dst[(size_t)rr * HOUT + wcol] = o;
        }
    }
}

// ---------------------------------------------------------------------------
// SpMM (CSR gather): S[row] += sum_e val[e]*Hg[col[e]]. One (HH/2)-lane group
// per row, float2 per lane (halves gather/FMA instruction count vs scalar).
// Optionally accumulates BN batch stats with striped atomics.
// ---------------------------------------------------------------------------

template <int HH, bool STATS>
__global__ __launch_bounds__(256) void spmm_k(
    const int* __restrict__ rowptr, const int2* __restrict__ cs,
    const float* __restrict__ Hg,
    float* __restrict__ S, float* __restrict__ stats, int n)
{
    constexpr int L  = HH / 2;            // lanes per group (float2 each)
    constexpr int GP = 256 / L;           // groups per block
    const int lane = threadIdx.x % L;
    const int g = threadIdx.x / L;
    const int gid = blockIdx.x * GP + g;
    const int ngroups = gridDim.x * GP;

    float2 sum = make_float2(0.f, 0.f), sq = make_float2(0.f, 0.f);
    for (int row = gid; row < n; row += ngroups) {
        int e0 = rowptr[row], e1 = rowptr[row + 1];
        float2 acc0 = *(const float2*)&S[(size_t)row * HH + lane * 2]; // h_node already here
        float2 acc1 = make_float2(0.f, 0.f);
        int e = e0;
        for (; e + 1 < e1; e += 2) {               // 2-way unroll: break FMA chain
            int2 p0 = cs[e], p1 = cs[e + 1];
            float v0 = __int_as_float(p0.y), v1 = __int_as_float(p1.y);
            float2 h0 = *(const float2*)&Hg[(size_t)p0.x * HH + lane * 2];
            float2 h1 = *(const float2*)&Hg[(size_t)p1.x * HH + lane * 2];
            acc0.x += v0 * h0.x; acc0.y += v0 * h0.y;
            acc1.x += v1 * h1.x; acc1.y += v1 * h1.y;
        }
        if (e < e1) {
            int2 p = cs[e];
            float v = __int_as_float(p.y);
            float2 h = *(const float2*)&Hg[(size_t)p.x * HH + lane * 2];
            acc0.x += v * h.x; acc0.y += v * h.y;
        }
        float2 acc = make_float2(acc0.x + acc1.x, acc0.y + acc1.y);
        *(float2*)&S[(size_t)row * HH + lane * 2] = acc;
        if (STATS) {
            sum.x += acc.x; sum.y += acc.y;
            sq.x += acc.x * acc.x; sq.y += acc.y * acc.y;
        }
    }

    if constexpr (STATS) {
        __shared__ float rs[GP][HH];
        __shared__ float rq[GP][HH];
        rs[g][lane * 2] = sum.x; rs[g][lane * 2 + 1] = sum.y;
        rq[g][lane * 2] = sq.x;  rq[g][lane * 2 + 1] = sq.y;
        __syncthreads();
        if (threadIdx.x < HH) {
            float a = 0.f, b = 0.f;
            for (int w = 0; w < GP; w++) { a += rs[w][threadIdx.x]; b += rq[w][threadIdx.x]; }
            int stripe = blockIdx.x & 7;
            atomicAdd(&stats[stripe * 128 + threadIdx.x], a);
            atomicAdd(&stats[stripe * 128 + HH + threadIdx.x], b);
        }
    }
}

// stats_in: 8 stripes x [sum[64] | sumsq[64]]. Writes BN scale/shift.
__global__ void finalize_k(const float* __restrict__ stats_in,
                           const float* __restrict__ gamma, const float* __restrict__ beta,
                           float* __restrict__ scale, float* __restrict__ shift, float n) {
    int t = threadIdx.x;   // 64
    float sum = 0.f, sq = 0.f;
    for (int s = 0; s < 8; s++) { sum += stats_in[s * 128 + t]; sq += stats_in[s * 128 + 64 + t]; }
    float m = sum / n;
    float var = sq / n - m * m;
    float sc = gamma[t] * rsqrtf(var + BN_EPS);
    scale[t] = sc;
    shift[t] = beta[t] - m * sc;
}

__global__ void gather_k(const float* __restrict__ S, const int* __restrict__ idx,
                         float* __restrict__ out, int total4) {
    int j = blockIdx.x * 256 + threadIdx.x;   // one float4 per thread
    if (j < total4) {
        int r = j / (EMB / 4), c4 = (j % (EMB / 4)) * 4;
        *(float4*)&out[(size_t)j * 4] = *(const float4*)&S[(size_t)idx[r] * EMB + c4];
    }
}

// ---------------------------------------------------------------------------

extern "C" void kernel_launch(void* const* d_in, const int* in_sizes, int n_in,
                              void* d_out, int out_size, void* d_ws, size_t ws_size,
                              hipStream_t stream) {
    const float* features = (const float*)d_in[0];
    const int*   rows     = (const int*)d_in[1];
    const int*   cols     = (const int*)d_in[2];
    const float* vals     = (const float*)d_in[3];
    const int*   idx      = (const int*)d_in[4];
    const float* Wn0 = (const float*)d_in[5];
    const float* bn0 = (const float*)d_in[6];
    const float* Wg0 = (const float*)d_in[7];
    const float* bg0 = (const float*)d_in[8];
    const float* ab0 = (const float*)d_in[9];
    const float* g0  = (const float*)d_in[10];
    const float* b0  = (const float*)d_in[11];
    const float* Wn1 = (const float*)d_in[12];
    const float* Wg1 = (const float*)d_in[13];
    const float* ab1 = (const float*)d_in[14];
    const float* g1  = (const float*)d_in[15];
    const float* b1  = (const float*)d_in[16];
    const float* WnL = (const float*)d_in[17];
    const float* WgL = (const float*)d_in[18];
    const float* abL = (const float*)d_in[19];
    float* out = (float*)d_out;

    // Workspace layout (~85 MB): 3 big activation buffers (reused), CSR, stats.
    float* big0 = (float*)d_ws;                         // Hn0/s0, then HnL/sL
    float* big1 = big0 + (size_t)NNODES * HID;          // Hg0/Hg1, then HgL
    float* big2 = big1 + (size_t)NNODES * HID;          // Hn1/s1
    int*   cnt     = (int*)(big2 + (size_t)NNODES * HID);
    int*   part    = cnt + NNODES;
    int*   rowptr  = part + 1024;
    int*   cursor  = rowptr + NNODES + 1;
    int2*  cs      = (int2*)(cursor + NNODES);          // packed {col, val_bits}
    float* stats   = (float*)(cs + NEDGES);
    float* sums0  = stats;
    float* sums1  = stats + 1024;
    float* scale0 = stats + 2048;
    float* shift0 = stats + 2112;
    float* scale1 = stats + 2176;
    float* shift1 = stats + 2240;

    hipMemsetAsync(cnt, 0, NNODES * sizeof(int), stream);
    hipMemsetAsync(stats, 0, 2048 * sizeof(float), stream);

    const int EB = (NEDGES + 255) / 256;   // 3125
    const int NB = (NNODES + 255) / 256;   // 391
    hist_k<<<EB, 256, 0, stream>>>(rows, cnt, NEDGES);
    scan1_k<<<NB, 256, 0, stream>>>(cnt, part, NNODES);
    scan2_k<<<1, 512, 0, stream>>>(part, NB);
    scan3_k<<<NB, 256, 0, stream>>>(cnt, part, rowptr, cursor, NNODES, NEDGES);
    scatter_k<<<EB, 256, 0, stream>>>(rows, cols, vals, cursor, cs, NEDGES);

    const int GB = (NNODES + 127) / 128;   // 782

    // Layer 0: Hn = X@Wn0 + bn0 + ab0, Hg = X@Wg0 + bg0; s0 = Hn + A@Hg
    gemm2_k<DIN, HID, false><<<GB, 256, 0, stream>>>(
        features, Wn0, Wg0, bn0, ab0, bg0, nullptr, nullptr, big0, big1, NNODES);
    spmm_k<HID, true><<<1600, 256, 0, stream>>>(rowptr, cs, big1, big0, sums0, NNODES);
    finalize_k<<<1, 64, 0, stream>>>(sums0, g0, b0, scale0, shift0, (float)NNODES);

    // Layer 1: x1 = relu(BN(s0)) folded into staging; s1 = Hn1 + A@Hg1 + ab1
    gemm2_k<HID, HID, true><<<GB, 256, 0, stream>>>(
        big0, Wn1, Wg1, ab1, nullptr, nullptr, scale0, shift0, big2, big1, NNODES);
    spmm_k<HID, true><<<1600, 256, 0, stream>>>(rowptr, cs, big1, big2, sums1, NNODES);
    finalize_k<<<1, 64, 0, stream>>>(sums1, g1, b1, scale1, shift1, (float)NNODES);

    // Last: xL = relu(BN(s1)); sL = xL@WnL + A@(xL@WgL) + abL; out = sL[idx]
    gemm2_k<HID, EMB, true><<<GB, 256, 0, stream>>>(
        big2, WnL, WgL, abL, nullptr, nullptr, scale1, shift1, big0, big1, NNODES);
    spmm_k<EMB, false><<<1600, 256, 0, stream>>>(rowptr, cs, big1, big0, nullptr, NNODES);
    gather_k<<<(NIDX * EMB / 4 + 255) / 256, 256, 0, stream>>>(big0, idx, out, NIDX * EMB / 4);
}